// Round 7
// baseline (707.633 us; speedup 1.0000x reference)
//
#include <hip/hip_runtime.h>
#include <hip/hip_bf16.h>

#define B_ 8
#define C_ 512
#define T_ 8192
#define P_ 512
#define K_ 30

typedef __attribute__((ext_vector_type(8))) short bf16x8;
typedef __attribute__((ext_vector_type(4))) float f32x4;

__device__ __forceinline__ unsigned short f2bf(float f) {
    union { float f; unsigned u; } v; v.f = f;
    unsigned r = v.u + 0x7fff + ((v.u >> 16) & 1);   // RTNE
    return (unsigned short)(r >> 16);
}

// ---------------------------------------------------------------------------
// Convert fp32 -> bf16 (n divisible by 4)
// ---------------------------------------------------------------------------
__global__ __launch_bounds__(256) void f32_to_bf16_kernel(
    const float* __restrict__ in, unsigned short* __restrict__ out, int n)
{
    int i = (blockIdx.x * 256 + threadIdx.x) * 4;
    if (i < n) {
        float4 v = *(const float4*)(in + i);
        ushort4 o;
        o.x = f2bf(v.x); o.y = f2bf(v.y); o.z = f2bf(v.z); o.w = f2bf(v.w);
        *(ushort4*)(out + i) = o;
    }
}

// ---------------------------------------------------------------------------
// Kernel 1: segment-mean pooling. boxes staged as INT32 [B,P,2] by harness.
// One block per (b,p), 4 waves; wave owns channels c = wave, wave+4, ...
// Writes bf16 feats [4096][512].
// ---------------------------------------------------------------------------
__global__ __launch_bounds__(256) void pool_kernel(
    const float* __restrict__ x, const int* __restrict__ boxes,
    unsigned short* __restrict__ feats)
{
    int bp = blockIdx.x;          // b*P + p
    int b  = bp >> 9;
    int s  = boxes[2 * bp];
    int e  = boxes[2 * bp + 1];
    float inv = 1.0f / (float)(e - s);
    const float* xb = x + (size_t)b * C_ * T_;
    int lane = threadIdx.x & 63;
    int wave = threadIdx.x >> 6;

    for (int c = wave; c < C_; c += 4) {
        const float* row = xb + (size_t)c * T_;
        float acc = 0.f;
        for (int t = s + lane; t < e; t += 64) acc += row[t];
        #pragma unroll
        for (int off = 32; off; off >>= 1) acc += __shfl_xor(acc, off);
        if (lane == 0) feats[(size_t)bp * C_ + c] = f2bf(acc * inv);
    }
}

// ---------------------------------------------------------------------------
// MFMA bf16 NT-GEMM: C[M,N] = A[M,K] * Bw[N,K]^T + bias (+ReLU).
// A, Bw bf16 row-major (K-contiguous). 256 thr = 4 waves (2x2), each wave
// computes 64x64 via 4x4 fragments of mfma_f32_16x16x32_bf16.
// Fragment layouts (verified, learn_hip m89/m91):
//   A: lane holds A[m= lane&15][k = k0 + (lane>>4)*8 + j], j=0..7 (contig 16B)
//   B: lane holds B[k][n= lane&15], same k-chunk -> contig 16B from Bw row
//   D: col = lane&15, row = (lane>>4)*4 + reg
// ---------------------------------------------------------------------------
template<int K, int RELU, int OUT_BF16>
__global__ __launch_bounds__(256) void gemm_mfma(
    const unsigned short* __restrict__ A, const unsigned short* __restrict__ Bw,
    const float* __restrict__ bias, void* __restrict__ out, int N)
{
    int tid  = threadIdx.x;
    int lane = tid & 63;
    int w    = tid >> 6;          // 0..3
    int lr   = lane & 15;
    int lk   = (lane >> 4) * 8;

    int m_base = blockIdx.y * 128 + (w & 1) * 64;
    int n_base = blockIdx.x * 128 + (w >> 1) * 64;

    const unsigned short* Ap = A + (size_t)(m_base + lr) * K + lk;
    const unsigned short* Bp = Bw + (size_t)(n_base + lr) * K + lk;

    f32x4 acc[4][4] = {};

    for (int k0 = 0; k0 < K; k0 += 32) {
        bf16x8 a[4], b[4];
        #pragma unroll
        for (int mi = 0; mi < 4; ++mi)
            a[mi] = *(const bf16x8*)(Ap + (size_t)mi * 16 * K + k0);
        #pragma unroll
        for (int ni = 0; ni < 4; ++ni)
            b[ni] = *(const bf16x8*)(Bp + (size_t)ni * 16 * K + k0);
        #pragma unroll
        for (int mi = 0; mi < 4; ++mi)
            #pragma unroll
            for (int ni = 0; ni < 4; ++ni)
                acc[mi][ni] = __builtin_amdgcn_mfma_f32_16x16x32_bf16(
                    a[mi], b[ni], acc[mi][ni], 0, 0, 0);
    }

    int rbase0 = (lane >> 4) * 4;
    #pragma unroll
    for (int ni = 0; ni < 4; ++ni) {
        int col = n_base + ni * 16 + lr;
        float bv = bias[col];
        #pragma unroll
        for (int mi = 0; mi < 4; ++mi) {
            int rbase = m_base + mi * 16 + rbase0;
            #pragma unroll
            for (int r = 0; r < 4; ++r) {
                float v = acc[mi][ni][r] + bv;
                if (RELU) v = fmaxf(v, 0.f);
                if (OUT_BF16)
                    ((unsigned short*)out)[(size_t)(rbase + r) * N + col] = f2bf(v);
                else
                    ((float*)out)[(size_t)(rbase + r) * N + col] = v;
            }
        }
    }
}

// ---------------------------------------------------------------------------
// Kernel 4: heads. One wave per row (bp). 30 class + 30 det logits,
// fused class softmax (over K) -> class_prob. h7 is fp32.
// ---------------------------------------------------------------------------
__global__ __launch_bounds__(64) void heads_kernel(
    const float* __restrict__ h7,
    const float* __restrict__ Wc, const float* __restrict__ bc,
    const float* __restrict__ Wd, const float* __restrict__ bd,
    float* __restrict__ class_logits, float* __restrict__ det_logits,
    float* __restrict__ class_prob)
{
    int bp = blockIdx.x;
    int lane = threadIdx.x;    // 0..63
    const float* hrow = h7 + (size_t)bp * 512;

    float h[8];
    #pragma unroll
    for (int j = 0; j < 8; ++j) h[j] = hrow[lane + 64 * j];

    __shared__ float sm[64];

    for (int k = 0; k < K_; ++k) {
        const float* w = Wc + (size_t)k * 512;
        float acc = 0.f;
        #pragma unroll
        for (int j = 0; j < 8; ++j) acc += h[j] * w[lane + 64 * j];
        #pragma unroll
        for (int off = 32; off; off >>= 1) acc += __shfl_xor(acc, off);
        if (lane == 0) sm[k] = acc + bc[k];
    }
    for (int k = 0; k < K_; ++k) {
        const float* w = Wd + (size_t)k * 512;
        float acc = 0.f;
        #pragma unroll
        for (int j = 0; j < 8; ++j) acc += h[j] * w[lane + 64 * j];
        #pragma unroll
        for (int off = 32; off; off >>= 1) acc += __shfl_xor(acc, off);
        if (lane == 0) sm[K_ + k] = acc + bd[k];
    }
    __syncthreads();

    float lc = (lane < K_) ? sm[lane] : -3.4e38f;
    if (lane < K_) {
        class_logits[(size_t)bp * K_ + lane] = lc;
        det_logits[(size_t)bp * K_ + lane]   = sm[K_ + lane];
    }
    float mx = lc;
    #pragma unroll
    for (int off = 32; off; off >>= 1) mx = fmaxf(mx, __shfl_xor(mx, off));
    float ex = (lane < K_) ? __expf(lc - mx) : 0.f;
    float sum = ex;
    #pragma unroll
    for (int off = 32; off; off >>= 1) sum += __shfl_xor(sum, off);
    if (lane < K_) class_prob[(size_t)bp * K_ + lane] = ex / sum;
}

// ---------------------------------------------------------------------------
// Kernel 5: det softmax over P (per b,k), joint prob, video prob.
// class_prob aliases joint: each element is read before being overwritten
// by the same thread at the same index.
// ---------------------------------------------------------------------------
__global__ __launch_bounds__(256) void det_softmax_kernel(
    const float* __restrict__ det_logits, const float* __restrict__ class_prob,
    float* __restrict__ joint, float* __restrict__ video)
{
    int k = blockIdx.x;
    int b = blockIdx.y;
    int tid = threadIdx.x;
    size_t base = (size_t)b * P_ * K_ + k;

    float v0 = det_logits[base + (size_t)tid * K_];
    float v1 = det_logits[base + (size_t)(tid + 256) * K_];

    __shared__ float red[256];
    red[tid] = fmaxf(v0, v1);
    __syncthreads();
    for (int off = 128; off; off >>= 1) {
        if (tid < off) red[tid] = fmaxf(red[tid], red[tid + off]);
        __syncthreads();
    }
    float mx = red[0];
    __syncthreads();

    float e0 = __expf(v0 - mx), e1 = __expf(v1 - mx);
    red[tid] = e0 + e1;
    __syncthreads();
    for (int off = 128; off; off >>= 1) {
        if (tid < off) red[tid] += red[tid + off];
        __syncthreads();
    }
    float inv = 1.0f / red[0];
    __syncthreads();

    float j0 = class_prob[base + (size_t)tid * K_] * e0 * inv;
    float j1 = class_prob[base + (size_t)(tid + 256) * K_] * e1 * inv;
    joint[base + (size_t)tid * K_] = j0;
    joint[base + (size_t)(tid + 256) * K_] = j1;

    red[tid] = j0 + j1;
    __syncthreads();
    for (int off = 128; off; off >>= 1) {
        if (tid < off) red[tid] += red[tid + off];
        __syncthreads();
    }
    if (tid == 0) video[(size_t)b * K_ + k] = red[0];
}

// ---------------------------------------------------------------------------
extern "C" void kernel_launch(void* const* d_in, const int* in_sizes, int n_in,
                              void* d_out, int out_size, void* d_ws, size_t ws_size,
                              hipStream_t stream)
{
    const float* x     = (const float*)d_in[0];
    const int*   boxes = (const int*)d_in[1];   // harness stages integers as int32
    const float* W6 = (const float*)d_in[2];
    const float* b6 = (const float*)d_in[3];
    const float* W7 = (const float*)d_in[4];
    const float* b7 = (const float*)d_in[5];
    const float* Wc = (const float*)d_in[6];
    const float* bc = (const float*)d_in[7];
    const float* Wd = (const float*)d_in[8];
    const float* bd = (const float*)d_in[9];

    float* out          = (float*)d_out;
    float* video        = out;                 // [8,30]        240
    float* joint        = out + 240;           // [8,512,30]    122880
    float* class_logits = out + 123120;        // [8,512,30]    122880
    float* det_logits   = out + 246000;        // [8,512,30]    122880
    float* h7           = out + 368880;        // [8,512,512]   2097152

    // Aliases into d_out (provably safe by kernel ordering):
    //  - feats (4 MB bf16) lives in h7's region: pool writes -> gemm1 reads ->
    //    dead before gemm2 writes h7.
    //  - class_prob lives in joint's region: heads writes -> det_softmax reads
    //    element i then overwrites element i (same thread).
    unsigned short* feats = (unsigned short*)h7;
    float* class_prob     = joint;

    // workspace (10 MB): h6 + bf16 weight copies
    unsigned short* h6  = (unsigned short*)d_ws;             // 4096*1024 bf16 (8 MB)
    unsigned short* w6b = h6 + (size_t)4096 * 1024;          // 1024*512 bf16 (1 MB)
    unsigned short* w7b = w6b + (size_t)1024 * 512;          // 512*1024 bf16 (1 MB)

    const int M = B_ * P_;   // 4096

    f32_to_bf16_kernel<<<512, 256, 0, stream>>>(W6, w6b, 1024 * 512);
    f32_to_bf16_kernel<<<512, 256, 0, stream>>>(W7, w7b, 512 * 1024);

    pool_kernel<<<M, 256, 0, stream>>>(x, boxes, feats);

    gemm_mfma<512, 1, 1><<<dim3(1024 / 128, M / 128), 256, 0, stream>>>(
        feats, w6b, b6, (void*)h6, 1024);

    gemm_mfma<1024, 1, 0><<<dim3(512 / 128, M / 128), 256, 0, stream>>>(
        h6, w7b, b7, (void*)h7, 512);

    heads_kernel<<<M, 64, 0, stream>>>(
        h7, Wc, bc, Wd, bd, class_logits, det_logits, class_prob);

    det_softmax_kernel<<<dim3(K_, B_), 256, 0, stream>>>(
        det_logits, class_prob, joint, video);
}

// Round 8
// 319.048 us; speedup vs baseline: 2.2180x; 2.2180x over previous
//
#include <hip/hip_runtime.h>
#include <hip/hip_bf16.h>

#define B_ 8
#define C_ 512
#define T_ 8192
#define P_ 512
#define K_ 30

typedef __attribute__((ext_vector_type(8))) short bf16x8;
typedef __attribute__((ext_vector_type(4))) float f32x4;

__device__ __forceinline__ unsigned short f2bf(float f) {
    union { float f; unsigned u; } v; v.f = f;
    unsigned r = v.u + 0x7fff + ((v.u >> 16) & 1);   // RTNE
    return (unsigned short)(r >> 16);
}

// padded LDS index: stride 33 words per 32-element chunk -> 2-way conflicts max
#define SCAN_PAD(i) ((i) + ((i) >> 5))

// ---------------------------------------------------------------------------
// Convert fp32 -> bf16 (n divisible by 4)
// ---------------------------------------------------------------------------
__global__ __launch_bounds__(256) void f32_to_bf16_kernel(
    const float* __restrict__ in, unsigned short* __restrict__ out, int n)
{
    int i = (blockIdx.x * 256 + threadIdx.x) * 4;
    if (i < n) {
        float4 v = *(const float4*)(in + i);
        ushort4 o;
        o.x = f2bf(v.x); o.y = f2bf(v.y); o.z = f2bf(v.z); o.w = f2bf(v.w);
        *(ushort4*)(out + i) = o;
    }
}

// ---------------------------------------------------------------------------
// Kernel 1a: per-(b,c)-row prefix-sum pooling. One block per row.
// Load row once (coalesced), block-scan in LDS, then every proposal is a
// single subtraction. Writes featsT[b][c][p] (coalesced in p).
// ---------------------------------------------------------------------------
__global__ __launch_bounds__(256) void pool_scan_kernel(
    const float* __restrict__ x, const int* __restrict__ boxes,
    unsigned short* __restrict__ featsT)
{
    __shared__ float cs[8448];       // 8192 + pad (33.8 KB)
    __shared__ float wtot[4];

    int bc  = blockIdx.x;            // b*C + c
    int b   = bc >> 9;
    int tid = threadIdx.x;
    int lane = tid & 63, wave = tid >> 6;

    const float* row = x + (size_t)bc * T_;
    for (int i = tid; i < T_; i += 256)
        cs[SCAN_PAD(i)] = row[i];
    __syncthreads();

    // per-thread sequential scan of its 32-element chunk
    int base = tid * 32;
    float run = 0.f;
    #pragma unroll
    for (int i = 0; i < 32; ++i) {
        run += cs[SCAN_PAD(base + i)];
        cs[SCAN_PAD(base + i)] = run;
    }

    // block-wide exclusive prefix of the 256 chunk totals
    float v = run;
    #pragma unroll
    for (int off = 1; off < 64; off <<= 1) {
        float n = __shfl_up(v, off);
        if (lane >= off) v += n;
    }
    if (lane == 63) wtot[wave] = v;
    __syncthreads();
    float waveoff = 0.f;
    #pragma unroll
    for (int wv = 0; wv < 4; ++wv)
        if (wv < wave) waveoff += wtot[wv];
    float excl = (v - run) + waveoff;

    #pragma unroll
    for (int i = 0; i < 32; ++i)
        cs[SCAN_PAD(base + i)] += excl;
    __syncthreads();

    // proposals: segment mean = (cs[e-1] - cs[s-1]) / (e-s)
    const int* bx = boxes + b * P_ * 2;
    for (int p = tid; p < P_; p += 256) {
        int s = bx[2 * p], e = bx[2 * p + 1];
        float hi = cs[SCAN_PAD(e - 1)];
        float lo = (s > 0) ? cs[SCAN_PAD(s - 1)] : 0.f;
        featsT[(size_t)bc * P_ + p] = f2bf((hi - lo) / (float)(e - s));
    }
}

// ---------------------------------------------------------------------------
// Kernel 1b: transpose featsT[b][c][p] -> feats[b*P+p][c] (bf16, 64x64 tiles)
// ---------------------------------------------------------------------------
__global__ __launch_bounds__(256) void transpose_kernel(
    const unsigned short* __restrict__ featsT, unsigned short* __restrict__ feats)
{
    __shared__ unsigned short tile[64][68];
    int c0 = blockIdx.x * 64;
    int p0 = blockIdx.y * 64;
    int b  = blockIdx.z;
    int tid = threadIdx.x;
    int tx = tid & 15;
    int ty = tid >> 4;

    #pragma unroll
    for (int rr = 0; rr < 4; ++rr) {
        int c = rr * 16 + ty;
        ushort4 v = *(const ushort4*)(featsT +
            ((size_t)(b * C_ + c0 + c) * P_ + p0 + tx * 4));
        tile[c][tx * 4 + 0] = v.x; tile[c][tx * 4 + 1] = v.y;
        tile[c][tx * 4 + 2] = v.z; tile[c][tx * 4 + 3] = v.w;
    }
    __syncthreads();
    #pragma unroll
    for (int rr = 0; rr < 4; ++rr) {
        int p = rr * 16 + ty;
        ushort4 o;
        o.x = tile[tx * 4 + 0][p]; o.y = tile[tx * 4 + 1][p];
        o.z = tile[tx * 4 + 2][p]; o.w = tile[tx * 4 + 3][p];
        *(ushort4*)(feats + ((size_t)(b * P_ + p0 + p) * C_ + c0 + tx * 4)) = o;
    }
}

// ---------------------------------------------------------------------------
// MFMA bf16 NT-GEMM: C[M,N] = A[M,K] * Bw[N,K]^T + bias (+ReLU).
// 256 thr = 4 waves (2x2), each wave 64x64 via 4x4 frags of 16x16x32.
// ---------------------------------------------------------------------------
template<int K, int RELU, int OUT_BF16>
__global__ __launch_bounds__(256) void gemm_mfma(
    const unsigned short* __restrict__ A, const unsigned short* __restrict__ Bw,
    const float* __restrict__ bias, void* __restrict__ out, int N)
{
    int tid  = threadIdx.x;
    int lane = tid & 63;
    int w    = tid >> 6;          // 0..3
    int lr   = lane & 15;
    int lk   = (lane >> 4) * 8;

    int m_base = blockIdx.y * 128 + (w & 1) * 64;
    int n_base = blockIdx.x * 128 + (w >> 1) * 64;

    const unsigned short* Ap = A + (size_t)(m_base + lr) * K + lk;
    const unsigned short* Bp = Bw + (size_t)(n_base + lr) * K + lk;

    f32x4 acc[4][4] = {};

    for (int k0 = 0; k0 < K; k0 += 32) {
        bf16x8 a[4], b[4];
        #pragma unroll
        for (int mi = 0; mi < 4; ++mi)
            a[mi] = *(const bf16x8*)(Ap + (size_t)mi * 16 * K + k0);
        #pragma unroll
        for (int ni = 0; ni < 4; ++ni)
            b[ni] = *(const bf16x8*)(Bp + (size_t)ni * 16 * K + k0);
        #pragma unroll
        for (int mi = 0; mi < 4; ++mi)
            #pragma unroll
            for (int ni = 0; ni < 4; ++ni)
                acc[mi][ni] = __builtin_amdgcn_mfma_f32_16x16x32_bf16(
                    a[mi], b[ni], acc[mi][ni], 0, 0, 0);
    }

    int rbase0 = (lane >> 4) * 4;
    #pragma unroll
    for (int ni = 0; ni < 4; ++ni) {
        int col = n_base + ni * 16 + lr;
        float bv = bias[col];
        #pragma unroll
        for (int mi = 0; mi < 4; ++mi) {
            int rbase = m_base + mi * 16 + rbase0;
            #pragma unroll
            for (int r = 0; r < 4; ++r) {
                float v = acc[mi][ni][r] + bv;
                if (RELU) v = fmaxf(v, 0.f);
                if (OUT_BF16)
                    ((unsigned short*)out)[(size_t)(rbase + r) * N + col] = f2bf(v);
                else
                    ((float*)out)[(size_t)(rbase + r) * N + col] = v;
            }
        }
    }
}

// ---------------------------------------------------------------------------
// Kernel 4: heads. One wave per row (bp). 30 class + 30 det logits,
// fused class softmax (over K) -> class_prob. h7 is fp32.
// ---------------------------------------------------------------------------
__global__ __launch_bounds__(64) void heads_kernel(
    const float* __restrict__ h7,
    const float* __restrict__ Wc, const float* __restrict__ bc,
    const float* __restrict__ Wd, const float* __restrict__ bd,
    float* __restrict__ class_logits, float* __restrict__ det_logits,
    float* __restrict__ class_prob)
{
    int bp = blockIdx.x;
    int lane = threadIdx.x;    // 0..63
    const float* hrow = h7 + (size_t)bp * 512;

    float h[8];
    #pragma unroll
    for (int j = 0; j < 8; ++j) h[j] = hrow[lane + 64 * j];

    __shared__ float sm[64];

    for (int k = 0; k < K_; ++k) {
        const float* w = Wc + (size_t)k * 512;
        float acc = 0.f;
        #pragma unroll
        for (int j = 0; j < 8; ++j) acc += h[j] * w[lane + 64 * j];
        #pragma unroll
        for (int off = 32; off; off >>= 1) acc += __shfl_xor(acc, off);
        if (lane == 0) sm[k] = acc + bc[k];
    }
    for (int k = 0; k < K_; ++k) {
        const float* w = Wd + (size_t)k * 512;
        float acc = 0.f;
        #pragma unroll
        for (int j = 0; j < 8; ++j) acc += h[j] * w[lane + 64 * j];
        #pragma unroll
        for (int off = 32; off; off >>= 1) acc += __shfl_xor(acc, off);
        if (lane == 0) sm[K_ + k] = acc + bd[k];
    }
    __syncthreads();

    float lc = (lane < K_) ? sm[lane] : -3.4e38f;
    if (lane < K_) {
        class_logits[(size_t)bp * K_ + lane] = lc;
        det_logits[(size_t)bp * K_ + lane]   = sm[K_ + lane];
    }
    float mx = lc;
    #pragma unroll
    for (int off = 32; off; off >>= 1) mx = fmaxf(mx, __shfl_xor(mx, off));
    float ex = (lane < K_) ? __expf(lc - mx) : 0.f;
    float sum = ex;
    #pragma unroll
    for (int off = 32; off; off >>= 1) sum += __shfl_xor(sum, off);
    if (lane < K_) class_prob[(size_t)bp * K_ + lane] = ex / sum;
}

// ---------------------------------------------------------------------------
// Kernel 5: det softmax over P (per b,k), joint prob, video prob.
// class_prob aliases joint: element read-before-write by same thread.
// ---------------------------------------------------------------------------
__global__ __launch_bounds__(256) void det_softmax_kernel(
    const float* __restrict__ det_logits, const float* __restrict__ class_prob,
    float* __restrict__ joint, float* __restrict__ video)
{
    int k = blockIdx.x;
    int b = blockIdx.y;
    int tid = threadIdx.x;
    size_t base = (size_t)b * P_ * K_ + k;

    float v0 = det_logits[base + (size_t)tid * K_];
    float v1 = det_logits[base + (size_t)(tid + 256) * K_];

    __shared__ float red[256];
    red[tid] = fmaxf(v0, v1);
    __syncthreads();
    for (int off = 128; off; off >>= 1) {
        if (tid < off) red[tid] = fmaxf(red[tid], red[tid + off]);
        __syncthreads();
    }
    float mx = red[0];
    __syncthreads();

    float e0 = __expf(v0 - mx), e1 = __expf(v1 - mx);
    red[tid] = e0 + e1;
    __syncthreads();
    for (int off = 128; off; off >>= 1) {
        if (tid < off) red[tid] += red[tid + off];
        __syncthreads();
    }
    float inv = 1.0f / red[0];
    __syncthreads();

    float j0 = class_prob[base + (size_t)tid * K_] * e0 * inv;
    float j1 = class_prob[base + (size_t)(tid + 256) * K_] * e1 * inv;
    joint[base + (size_t)tid * K_] = j0;
    joint[base + (size_t)(tid + 256) * K_] = j1;

    red[tid] = j0 + j1;
    __syncthreads();
    for (int off = 128; off; off >>= 1) {
        if (tid < off) red[tid] += red[tid + off];
        __syncthreads();
    }
    if (tid == 0) video[(size_t)b * K_ + k] = red[0];
}

// ---------------------------------------------------------------------------
extern "C" void kernel_launch(void* const* d_in, const int* in_sizes, int n_in,
                              void* d_out, int out_size, void* d_ws, size_t ws_size,
                              hipStream_t stream)
{
    const float* x     = (const float*)d_in[0];
    const int*   boxes = (const int*)d_in[1];   // harness stages integers as int32
    const float* W6 = (const float*)d_in[2];
    const float* b6 = (const float*)d_in[3];
    const float* W7 = (const float*)d_in[4];
    const float* b7 = (const float*)d_in[5];
    const float* Wc = (const float*)d_in[6];
    const float* bc = (const float*)d_in[7];
    const float* Wd = (const float*)d_in[8];
    const float* bd = (const float*)d_in[9];

    float* out          = (float*)d_out;
    float* video        = out;                 // [8,30]        240
    float* joint        = out + 240;           // [8,512,30]    122880
    float* class_logits = out + 123120;        // [8,512,30]    122880
    float* det_logits   = out + 246000;        // [8,512,30]    122880
    float* h7           = out + 368880;        // [8,512,512]   2097152 (8 MB)

    // Aliases into d_out (safe by kernel ordering):
    //  - feats (4 MB) + featsT (4 MB) exactly fill h7's 8 MB region; both are
    //    dead before gemm2 writes h7.
    //  - class_prob lives in joint's region: read-before-write per element.
    unsigned short* feats  = (unsigned short*)h7;
    unsigned short* featsT = feats + (size_t)4096 * 512;
    float* class_prob      = joint;

    // workspace (10 MB): h6 + bf16 weight copies
    unsigned short* h6  = (unsigned short*)d_ws;             // 4096*1024 bf16 (8 MB)
    unsigned short* w6b = h6 + (size_t)4096 * 1024;          // 1024*512 bf16 (1 MB)
    unsigned short* w7b = w6b + (size_t)1024 * 512;          // 512*1024 bf16 (1 MB)

    const int M = B_ * P_;   // 4096

    f32_to_bf16_kernel<<<512, 256, 0, stream>>>(W6, w6b, 1024 * 512);
    f32_to_bf16_kernel<<<512, 256, 0, stream>>>(W7, w7b, 512 * 1024);

    pool_scan_kernel<<<B_ * C_, 256, 0, stream>>>(x, boxes, featsT);

    transpose_kernel<<<dim3(C_ / 64, P_ / 64, B_), 256, 0, stream>>>(featsT, feats);

    gemm_mfma<512, 1, 1><<<dim3(1024 / 128, M / 128), 256, 0, stream>>>(
        feats, w6b, b6, (void*)h6, 1024);

    gemm_mfma<1024, 1, 0><<<dim3(512 / 128, M / 128), 256, 0, stream>>>(
        h6, w7b, b7, (void*)h7, 512);

    heads_kernel<<<M, 64, 0, stream>>>(
        h7, Wc, bc, Wd, bd, class_logits, det_logits, class_prob);

    det_softmax_kernel<<<dim3(K_, B_), 256, 0, stream>>>(
        det_logits, class_prob, joint, video);
}

// Round 11
// 293.330 us; speedup vs baseline: 2.4124x; 1.0877x over previous
//
#include <hip/hip_runtime.h>
#include <hip/hip_bf16.h>

#define B_ 8
#define C_ 512
#define T_ 8192
#define P_ 512
#define K_ 30

typedef __attribute__((ext_vector_type(8))) short bf16x8;
typedef __attribute__((ext_vector_type(4))) float f32x4;

__device__ __forceinline__ unsigned short f2bf(float f) {
    union { float f; unsigned u; } v; v.f = f;
    unsigned r = v.u + 0x7fff + ((v.u >> 16) & 1);   // RTNE
    return (unsigned short)(r >> 16);
}

// padded LDS index: +1 word per 32 -> lane-stride 33 words, conflict-free
#define SCAN_PAD(i) ((i) + ((i) >> 5))

// ---------------------------------------------------------------------------
// Kernel 1: fused {per-(b,c)-row prefix-sum pooling | weight prep}.
//  bid < 4096            : pool row bid (register scan + LDS gather)
//  4096 <= bid < 4608    : W6 f32->bf16   (512 blocks)
//  4608 <= bid < 5120    : W7 f32->bf16   (512 blocks)
//  5120 <= bid < 5184    : build wcd[64][512] bf16 (Wc rows 0-29, Wd rows
//                          32-61, zeros elsewhere) + bcd[64]
// ---------------------------------------------------------------------------
__global__ __launch_bounds__(256) void prep_pool_kernel(
    const float* __restrict__ x, const int* __restrict__ boxes,
    unsigned short* __restrict__ featsT,
    const float* __restrict__ W6, unsigned short* __restrict__ w6b,
    const float* __restrict__ W7, unsigned short* __restrict__ w7b,
    const float* __restrict__ Wc, const float* __restrict__ bcv,
    const float* __restrict__ Wd, const float* __restrict__ bdv,
    unsigned short* __restrict__ wcd, float* __restrict__ bcd)
{
    __shared__ float cs[8448];      // 8192 + pad
    __shared__ float wtot[4];

    int bid = blockIdx.x;
    int tid = threadIdx.x;

    if (bid >= 4096) {
        int j = bid - 4096;
        if (j < 512) {                       // W6 convert
            int i = j * 1024 + tid * 4;
            float4 v = *(const float4*)(W6 + i);
            ushort4 o; o.x = f2bf(v.x); o.y = f2bf(v.y);
            o.z = f2bf(v.z); o.w = f2bf(v.w);
            *(ushort4*)(w6b + i) = o;
        } else if (j < 1024) {               // W7 convert
            int i = (j - 512) * 1024 + tid * 4;
            float4 v = *(const float4*)(W7 + i);
            ushort4 o; o.x = f2bf(v.x); o.y = f2bf(v.y);
            o.z = f2bf(v.z); o.w = f2bf(v.w);
            *(ushort4*)(w7b + i) = o;
        } else {                             // combined head weights
            int r = j - 1024;                // 0..63
            const float* src = nullptr;
            float bias = 0.f;
            if (r < 30)                 { src = Wc + (size_t)r * 512;        bias = bcv[r]; }
            else if (r >= 32 && r < 62) { src = Wd + (size_t)(r - 32) * 512; bias = bdv[r - 32]; }
            #pragma unroll
            for (int q = 0; q < 2; ++q) {
                int c = tid + q * 256;
                wcd[(size_t)r * 512 + c] = src ? f2bf(src[c]) : (unsigned short)0;
            }
            if (tid == 0) bcd[r] = bias;
        }
        return;
    }

    // ---- pooling branch ----
    int bc = bid;                    // b*C + c
    int b  = bc >> 9;
    int lane = tid & 63, wave = tid >> 6;
    const float* row = x + (size_t)bc * T_;

    // load own 32-element chunk, scan in registers
    int base = tid * 32;
    float v[32];
    #pragma unroll
    for (int q = 0; q < 8; ++q)
        *(float4*)&v[q * 4] = *(const float4*)(row + base + q * 4);
    float run = 0.f;
    #pragma unroll
    for (int i = 0; i < 32; ++i) { run += v[i]; v[i] = run; }

    // wave-inclusive scan of chunk totals
    float sc = run;
    #pragma unroll
    for (int off = 1; off < 64; off <<= 1) {
        float n = __shfl_up(sc, off);
        if (lane >= off) sc += n;
    }
    if (lane == 63) wtot[wave] = sc;
    __syncthreads();
    float woff = 0.f;
    #pragma unroll
    for (int wv = 0; wv < 4; ++wv)
        if (wv < wave) woff += wtot[wv];
    float excl = (sc - run) + woff;

    #pragma unroll
    for (int i = 0; i < 32; ++i)
        cs[SCAN_PAD(base + i)] = v[i] + excl;
    __syncthreads();

    // proposals: mean = (cs[e-1] - cs[s-1]) / (e-s)
    const int* bx = boxes + b * P_ * 2;
    #pragma unroll
    for (int q = 0; q < 2; ++q) {
        int p = tid + q * 256;
        int s = bx[2 * p], e = bx[2 * p + 1];
        float hi = cs[SCAN_PAD(e - 1)];
        float lo = (s > 0) ? cs[SCAN_PAD(s - 1)] : 0.f;
        featsT[(size_t)bc * P_ + p] = f2bf((hi - lo) / (float)(e - s));
    }
}

// ---------------------------------------------------------------------------
// Kernel 2: transpose featsT[b][c][p] -> feats[b*P+p][c] (bf16, 64x64 tiles)
// ---------------------------------------------------------------------------
__global__ __launch_bounds__(256) void transpose_kernel(
    const unsigned short* __restrict__ featsT, unsigned short* __restrict__ feats)
{
    __shared__ unsigned short tile[64][68];
    int c0 = blockIdx.x * 64;
    int p0 = blockIdx.y * 64;
    int b  = blockIdx.z;
    int tid = threadIdx.x;
    int tx = tid & 15;
    int ty = tid >> 4;

    #pragma unroll
    for (int rr = 0; rr < 4; ++rr) {
        int c = rr * 16 + ty;
        ushort4 v = *(const ushort4*)(featsT +
            ((size_t)(b * C_ + c0 + c) * P_ + p0 + tx * 4));
        tile[c][tx * 4 + 0] = v.x; tile[c][tx * 4 + 1] = v.y;
        tile[c][tx * 4 + 2] = v.z; tile[c][tx * 4 + 3] = v.w;
    }
    __syncthreads();
    #pragma unroll
    for (int rr = 0; rr < 4; ++rr) {
        int p = rr * 16 + ty;
        ushort4 o;
        o.x = tile[tx * 4 + 0][p]; o.y = tile[tx * 4 + 1][p];
        o.z = tile[tx * 4 + 2][p]; o.w = tile[tx * 4 + 3][p];
        *(ushort4*)(feats + ((size_t)(b * P_ + p0 + p) * C_ + c0 + tx * 4)) = o;
    }
}

// ---------------------------------------------------------------------------
// MFMA bf16 NT-GEMM: C[M,N] = A[M,K] * Bw[N,K]^T + bias (+ReLU).
// 4 waves (2x2), wave = 64x64 via 4x4 frags of 16x16x32.
// MODE: 0 = f32 out, 1 = bf16 out, 2 = f32 out + bf16 out2 (dual)
// ---------------------------------------------------------------------------
template<int K, int RELU, int MODE>
__global__ __launch_bounds__(256) void gemm_mfma(
    const unsigned short* __restrict__ A, const unsigned short* __restrict__ Bw,
    const float* __restrict__ bias, void* __restrict__ out,
    unsigned short* __restrict__ out2, int N)
{
    int tid  = threadIdx.x;
    int lane = tid & 63;
    int w    = tid >> 6;
    int lr   = lane & 15;
    int lk   = (lane >> 4) * 8;

    int m_base = blockIdx.y * 128 + (w & 1) * 64;
    int n_base = blockIdx.x * 128 + (w >> 1) * 64;

    const unsigned short* Ap = A + (size_t)(m_base + lr) * K + lk;
    const unsigned short* Bp = Bw + (size_t)(n_base + lr) * K + lk;

    f32x4 acc[4][4] = {};

    for (int k0 = 0; k0 < K; k0 += 32) {
        bf16x8 a[4], b[4];
        #pragma unroll
        for (int mi = 0; mi < 4; ++mi)
            a[mi] = *(const bf16x8*)(Ap + (size_t)mi * 16 * K + k0);
        #pragma unroll
        for (int ni = 0; ni < 4; ++ni)
            b[ni] = *(const bf16x8*)(Bp + (size_t)ni * 16 * K + k0);
        #pragma unroll
        for (int mi = 0; mi < 4; ++mi)
            #pragma unroll
            for (int ni = 0; ni < 4; ++ni)
                acc[mi][ni] = __builtin_amdgcn_mfma_f32_16x16x32_bf16(
                    a[mi], b[ni], acc[mi][ni], 0, 0, 0);
    }

    int rbase0 = (lane >> 4) * 4;
    #pragma unroll
    for (int ni = 0; ni < 4; ++ni) {
        int col = n_base + ni * 16 + lr;
        float bv = bias[col];
        #pragma unroll
        for (int mi = 0; mi < 4; ++mi) {
            int rbase = m_base + mi * 16 + rbase0;
            #pragma unroll
            for (int r = 0; r < 4; ++r) {
                float v = acc[mi][ni][r] + bv;
                if (RELU) v = fmaxf(v, 0.f);
                size_t idx = (size_t)(rbase + r) * N + col;
                if (MODE == 1) ((unsigned short*)out)[idx] = f2bf(v);
                else           ((float*)out)[idx] = v;
                if (MODE == 2) out2[idx] = f2bf(v);
            }
        }
    }
}

// ---------------------------------------------------------------------------
// Kernel 5: heads GEMM. h7b[4096][512]bf16 @ wcd[64][512]^T + bcd.
// cols 0-29 -> class logits (+fused class softmax), 32-61 -> det logits.
// Grid 16 blocks x 4 waves; wave owns 64 rows x all 64 cols.
// For fixed (mi,r), the 16 lanes with equal lane>>4 hold one row's 64 cols
// -> class softmax reduces over shfl_xor 1,2,4,8.
// ---------------------------------------------------------------------------
__global__ __launch_bounds__(256) void heads_gemm_kernel(
    const unsigned short* __restrict__ h7b,
    const unsigned short* __restrict__ wcd, const float* __restrict__ bcd,
    float* __restrict__ class_logits, float* __restrict__ det_logits,
    float* __restrict__ class_prob)
{
    int tid  = threadIdx.x;
    int lane = tid & 63;
    int w    = tid >> 6;
    int lr   = lane & 15;
    int lk   = (lane >> 4) * 8;

    int m_base = blockIdx.x * 256 + w * 64;

    const unsigned short* Ap = h7b + (size_t)(m_base + lr) * 512 + lk;
    const unsigned short* Bp = wcd + (size_t)lr * 512 + lk;

    f32x4 acc[4][4] = {};

    for (int k0 = 0; k0 < 512; k0 += 32) {
        bf16x8 a[4], b[4];
        #pragma unroll
        for (int mi = 0; mi < 4; ++mi)
            a[mi] = *(const bf16x8*)(Ap + (size_t)mi * 16 * 512 + k0);
        #pragma unroll
        for (int ni = 0; ni < 4; ++ni)
            b[ni] = *(const bf16x8*)(Bp + (size_t)ni * 16 * 512 + k0);
        #pragma unroll
        for (int mi = 0; mi < 4; ++mi)
            #pragma unroll
            for (int ni = 0; ni < 4; ++ni)
                acc[mi][ni] = __builtin_amdgcn_mfma_f32_16x16x32_bf16(
                    a[mi], b[ni], acc[mi][ni], 0, 0, 0);
    }

    float b0 = bcd[lr], b1 = bcd[16 + lr], b2 = bcd[32 + lr], b3 = bcd[48 + lr];
    int rgrp = (lane >> 4) * 4;

    #pragma unroll
    for (int mi = 0; mi < 4; ++mi) {
        #pragma unroll
        for (int r = 0; r < 4; ++r) {
            int row = m_base + mi * 16 + rgrp + r;
            float c0 = acc[mi][0][r] + b0;
            float c1 = (lr < 14) ? (acc[mi][1][r] + b1) : -3.4e38f;
            // class softmax across the row (16-lane group)
            float mx = fmaxf(c0, c1);
            #pragma unroll
            for (int m = 1; m < 16; m <<= 1) mx = fmaxf(mx, __shfl_xor(mx, m));
            float e0 = __expf(c0 - mx);
            float e1 = (lr < 14) ? __expf(c1 - mx) : 0.f;
            float s = e0 + e1;
            #pragma unroll
            for (int m = 1; m < 16; m <<= 1) s += __shfl_xor(s, m);
            float inv = 1.0f / s;

            class_logits[(size_t)row * K_ + lr] = c0;
            class_prob[(size_t)row * K_ + lr]   = e0 * inv;
            det_logits[(size_t)row * K_ + lr]   = acc[mi][2][r] + b2;
            if (lr < 14) {
                class_logits[(size_t)row * K_ + 16 + lr] = c1;
                class_prob[(size_t)row * K_ + 16 + lr]   = e1 * inv;
                det_logits[(size_t)row * K_ + 16 + lr]   = acc[mi][3][r] + b3;
            }
        }
    }
}

// ---------------------------------------------------------------------------
// Kernel 6: det softmax over P (per b,k), joint prob, video prob.
// ---------------------------------------------------------------------------
__global__ __launch_bounds__(256) void det_softmax_kernel(
    const float* __restrict__ det_logits, const float* __restrict__ class_prob,
    float* __restrict__ joint, float* __restrict__ video)
{
    int k = blockIdx.x;
    int b = blockIdx.y;
    int tid = threadIdx.x;
    size_t base = (size_t)b * P_ * K_ + k;

    float v0 = det_logits[base + (size_t)tid * K_];
    float v1 = det_logits[base + (size_t)(tid + 256) * K_];

    __shared__ float red[256];
    red[tid] = fmaxf(v0, v1);
    __syncthreads();
    for (int off = 128; off; off >>= 1) {
        if (tid < off) red[tid] = fmaxf(red[tid], red[tid + off]);
        __syncthreads();
    }
    float mx = red[0];
    __syncthreads();

    float e0 = __expf(v0 - mx), e1 = __expf(v1 - mx);
    red[tid] = e0 + e1;
    __syncthreads();
    for (int off = 128; off; off >>= 1) {
        if (tid < off) red[tid] += red[tid + off];
        __syncthreads();
    }
    float inv = 1.0f / red[0];
    __syncthreads();

    float j0 = class_prob[base + (size_t)tid * K_] * e0 * inv;
    float j1 = class_prob[base + (size_t)(tid + 256) * K_] * e1 * inv;
    joint[base + (size_t)tid * K_] = j0;
    joint[base + (size_t)(tid + 256) * K_] = j1;

    red[tid] = j0 + j1;
    __syncthreads();
    for (int off = 128; off; off >>= 1) {
        if (tid < off) red[tid] += red[tid + off];
        __syncthreads();
    }
    if (tid == 0) video[(size_t)b * K_ + k] = red[0];
}

// ---------------------------------------------------------------------------
extern "C" void kernel_launch(void* const* d_in, const int* in_sizes, int n_in,
                              void* d_out, int out_size, void* d_ws, size_t ws_size,
                              hipStream_t stream)
{
    const float* x     = (const float*)d_in[0];
    const int*   boxes = (const int*)d_in[1];   // staged as int32
    const float* W6 = (const float*)d_in[2];
    const float* b6 = (const float*)d_in[3];
    const float* W7 = (const float*)d_in[4];
    const float* b7 = (const float*)d_in[5];
    const float* Wc = (const float*)d_in[6];
    const float* bc = (const float*)d_in[7];
    const float* Wd = (const float*)d_in[8];
    const float* bd = (const float*)d_in[9];

    float* out          = (float*)d_out;
    float* video        = out;                 // [8,30]
    float* joint        = out + 240;           // [8,512,30]
    float* class_logits = out + 123120;        // [8,512,30]
    float* det_logits   = out + 246000;        // [8,512,30]
    float* h7           = out + 368880;        // [8,512,512] f32

    // workspace (~23 MB of ~512 MB) — all regions 16B-aligned
    unsigned short* wsu   = (unsigned short*)d_ws;
    unsigned short* h6    = wsu;                                  // 4096*1024
    unsigned short* w6b   = h6 + (size_t)4096 * 1024;             // 1024*512
    unsigned short* w7b   = w6b + (size_t)1024 * 512;             // 512*1024
    unsigned short* wcd   = w7b + (size_t)512 * 1024;             // 64*512
    unsigned short* h7b   = wcd + (size_t)64 * 512;               // 4096*512
    unsigned short* feats = h7b + (size_t)4096 * 512;             // 4096*512
    unsigned short* featsT= feats + (size_t)4096 * 512;           // 4096*512
    float* bcd            = (float*)(featsT + (size_t)4096 * 512);// 64
    float* class_prob     = bcd + 64;                             // 122880

    const int M = B_ * P_;   // 4096

    prep_pool_kernel<<<5184, 256, 0, stream>>>(
        x, boxes, featsT, W6, w6b, W7, w7b, Wc, bc, Wd, bd, wcd, bcd);

    transpose_kernel<<<dim3(C_ / 64, P_ / 64, B_), 256, 0, stream>>>(featsT, feats);

    gemm_mfma<512, 1, 1><<<dim3(1024 / 128, M / 128), 256, 0, stream>>>(
        feats, w6b, b6, (void*)h6, nullptr, 1024);

    gemm_mfma<1024, 1, 2><<<dim3(512 / 128, M / 128), 256, 0, stream>>>(
        h6, w7b, b7, (void*)h7, h7b, 512);

    heads_gemm_kernel<<<16, 256, 0, stream>>>(
        h7b, wcd, bcd, class_logits, det_logits, class_prob);

    det_softmax_kernel<<<dim3(K_, B_), 256, 0, stream>>>(
        det_logits, class_prob, joint, video);
}

// Round 12
// 293.286 us; speedup vs baseline: 2.4128x; 1.0002x over previous
//
#include <hip/hip_runtime.h>
#include <hip/hip_bf16.h>

#define B_ 8
#define C_ 512
#define T_ 8192
#define P_ 512
#define K_ 30

typedef __attribute__((ext_vector_type(8))) short bf16x8;
typedef __attribute__((ext_vector_type(4))) float f32x4;

__device__ __forceinline__ unsigned short f2bf(float f) {
    union { float f; unsigned u; } v; v.f = f;
    unsigned r = v.u + 0x7fff + ((v.u >> 16) & 1);   // RTNE
    return (unsigned short)(r >> 16);
}

// padded LDS index: +1 word per 32 -> lane-stride 33 words, conflict-free
#define SCAN_PAD(i) ((i) + ((i) >> 5))

// ---------------------------------------------------------------------------
// Kernel 1: fused {per-(b,c)-row prefix-sum pooling | weight prep}.
//  bid < 4096            : pool row bid (register scan + LDS gather)
//  4096 <= bid < 4608    : W6 f32->bf16   (512 blocks)
//  4608 <= bid < 5120    : W7 f32->bf16   (512 blocks)
//  5120 <= bid < 5184    : build wcd[64][512] bf16 + bcd[64]
// ---------------------------------------------------------------------------
__global__ __launch_bounds__(256) void prep_pool_kernel(
    const float* __restrict__ x, const int* __restrict__ boxes,
    unsigned short* __restrict__ featsT,
    const float* __restrict__ W6, unsigned short* __restrict__ w6b,
    const float* __restrict__ W7, unsigned short* __restrict__ w7b,
    const float* __restrict__ Wc, const float* __restrict__ bcv,
    const float* __restrict__ Wd, const float* __restrict__ bdv,
    unsigned short* __restrict__ wcd, float* __restrict__ bcd)
{
    __shared__ float cs[8448];      // 8192 + pad
    __shared__ float wtot[4];

    int bid = blockIdx.x;
    int tid = threadIdx.x;

    if (bid >= 4096) {
        int j = bid - 4096;
        if (j < 512) {                       // W6 convert
            int i = j * 1024 + tid * 4;
            float4 v = *(const float4*)(W6 + i);
            ushort4 o; o.x = f2bf(v.x); o.y = f2bf(v.y);
            o.z = f2bf(v.z); o.w = f2bf(v.w);
            *(ushort4*)(w6b + i) = o;
        } else if (j < 1024) {               // W7 convert
            int i = (j - 512) * 1024 + tid * 4;
            float4 v = *(const float4*)(W7 + i);
            ushort4 o; o.x = f2bf(v.x); o.y = f2bf(v.y);
            o.z = f2bf(v.z); o.w = f2bf(v.w);
            *(ushort4*)(w7b + i) = o;
        } else {                             // combined head weights
            int r = j - 1024;                // 0..63
            const float* src = nullptr;
            float bias = 0.f;
            if (r < 30)                 { src = Wc + (size_t)r * 512;        bias = bcv[r]; }
            else if (r >= 32 && r < 62) { src = Wd + (size_t)(r - 32) * 512; bias = bdv[r - 32]; }
            #pragma unroll
            for (int q = 0; q < 2; ++q) {
                int c = tid + q * 256;
                wcd[(size_t)r * 512 + c] = src ? f2bf(src[c]) : (unsigned short)0;
            }
            if (tid == 0) bcd[r] = bias;
        }
        return;
    }

    // ---- pooling branch ----
    int bc = bid;                    // b*C + c
    int b  = bc >> 9;
    int lane = tid & 63, wave = tid >> 6;
    const float* row = x + (size_t)bc * T_;

    // load own 32-element chunk, scan in registers
    int base = tid * 32;
    float v[32];
    #pragma unroll
    for (int q = 0; q < 8; ++q)
        *(float4*)&v[q * 4] = *(const float4*)(row + base + q * 4);
    float run = 0.f;
    #pragma unroll
    for (int i = 0; i < 32; ++i) { run += v[i]; v[i] = run; }

    // wave-inclusive scan of chunk totals
    float sc = run;
    #pragma unroll
    for (int off = 1; off < 64; off <<= 1) {
        float n = __shfl_up(sc, off);
        if (lane >= off) sc += n;
    }
    if (lane == 63) wtot[wave] = sc;
    __syncthreads();
    float woff = 0.f;
    #pragma unroll
    for (int wv = 0; wv < 4; ++wv)
        if (wv < wave) woff += wtot[wv];
    float excl = (sc - run) + woff;

    #pragma unroll
    for (int i = 0; i < 32; ++i)
        cs[SCAN_PAD(base + i)] = v[i] + excl;
    __syncthreads();

    // proposals: mean = (cs[e-1] - cs[s-1]) / (e-s)
    const int* bx = boxes + b * P_ * 2;
    #pragma unroll
    for (int q = 0; q < 2; ++q) {
        int p = tid + q * 256;
        int s = bx[2 * p], e = bx[2 * p + 1];
        float hi = cs[SCAN_PAD(e - 1)];
        float lo = (s > 0) ? cs[SCAN_PAD(s - 1)] : 0.f;
        featsT[(size_t)bc * P_ + p] = f2bf((hi - lo) / (float)(e - s));
    }
}

// ---------------------------------------------------------------------------
// Kernel 2: transpose featsT[b][c][p] -> feats[b*P+p][c] (bf16, 64x64 tiles)
// ---------------------------------------------------------------------------
__global__ __launch_bounds__(256) void transpose_kernel(
    const unsigned short* __restrict__ featsT, unsigned short* __restrict__ feats)
{
    __shared__ unsigned short tile[64][68];
    int c0 = blockIdx.x * 64;
    int p0 = blockIdx.y * 64;
    int b  = blockIdx.z;
    int tid = threadIdx.x;
    int tx = tid & 15;
    int ty = tid >> 4;

    #pragma unroll
    for (int rr = 0; rr < 4; ++rr) {
        int c = rr * 16 + ty;
        ushort4 v = *(const ushort4*)(featsT +
            ((size_t)(b * C_ + c0 + c) * P_ + p0 + tx * 4));
        tile[c][tx * 4 + 0] = v.x; tile[c][tx * 4 + 1] = v.y;
        tile[c][tx * 4 + 2] = v.z; tile[c][tx * 4 + 3] = v.w;
    }
    __syncthreads();
    #pragma unroll
    for (int rr = 0; rr < 4; ++rr) {
        int p = rr * 16 + ty;
        ushort4 o;
        o.x = tile[tx * 4 + 0][p]; o.y = tile[tx * 4 + 1][p];
        o.z = tile[tx * 4 + 2][p]; o.w = tile[tx * 4 + 3][p];
        *(ushort4*)(feats + ((size_t)(b * P_ + p0 + p) * C_ + c0 + tx * 4)) = o;
    }
}

// ---------------------------------------------------------------------------
// MFMA bf16 NT-GEMM with depth-2 register pipeline.
// Block = 256 thr = 4 waves arranged (BM/WM)x(BN/WN); wave tile WM x WN via
// (WM/16)x(WN/16) frags of 16x16x32. Grid (N/BN, M/BM).
// MODE: 0 = f32 out, 1 = bf16 out, 2 = f32 out + bf16 out2 (dual)
// ---------------------------------------------------------------------------
template<int K, int RELU, int MODE, int BM, int BN, int WM, int WN>
__global__ __launch_bounds__(256) void gemm_mfma(
    const unsigned short* __restrict__ A, const unsigned short* __restrict__ Bw,
    const float* __restrict__ bias, void* __restrict__ out,
    unsigned short* __restrict__ out2, int N)
{
    constexpr int MI = WM / 16;
    constexpr int NI = WN / 16;
    constexpr int WAVES_N = BN / WN;

    int tid  = threadIdx.x;
    int lane = tid & 63;
    int w    = tid >> 6;
    int lr   = lane & 15;
    int lk   = (lane >> 4) * 8;

    int wm = w / WAVES_N;
    int wn = w % WAVES_N;
    int m_off = blockIdx.y * BM + wm * WM;
    int n_off = blockIdx.x * BN + wn * WN;

    const unsigned short* Ap = A + (size_t)(m_off + lr) * K + lk;
    const unsigned short* Bp = Bw + (size_t)(n_off + lr) * K + lk;

    f32x4 acc[MI][NI] = {};
    bf16x8 aC[MI], bC[NI], aN[MI], bN[NI];

    // prologue: chunk 0
    #pragma unroll
    for (int mi = 0; mi < MI; ++mi)
        aC[mi] = *(const bf16x8*)(Ap + (size_t)mi * 16 * K);
    #pragma unroll
    for (int ni = 0; ni < NI; ++ni)
        bC[ni] = *(const bf16x8*)(Bp + (size_t)ni * 16 * K);

    #pragma unroll
    for (int k0 = 0; k0 < K; k0 += 64) {
        // load chunk k0+32 while computing chunk k0
        #pragma unroll
        for (int mi = 0; mi < MI; ++mi)
            aN[mi] = *(const bf16x8*)(Ap + (size_t)mi * 16 * K + k0 + 32);
        #pragma unroll
        for (int ni = 0; ni < NI; ++ni)
            bN[ni] = *(const bf16x8*)(Bp + (size_t)ni * 16 * K + k0 + 32);
        #pragma unroll
        for (int mi = 0; mi < MI; ++mi)
            #pragma unroll
            for (int ni = 0; ni < NI; ++ni)
                acc[mi][ni] = __builtin_amdgcn_mfma_f32_16x16x32_bf16(
                    aC[mi], bC[ni], acc[mi][ni], 0, 0, 0);
        // load chunk k0+64 while computing chunk k0+32
        if (k0 + 64 < K) {
            #pragma unroll
            for (int mi = 0; mi < MI; ++mi)
                aC[mi] = *(const bf16x8*)(Ap + (size_t)mi * 16 * K + k0 + 64);
            #pragma unroll
            for (int ni = 0; ni < NI; ++ni)
                bC[ni] = *(const bf16x8*)(Bp + (size_t)ni * 16 * K + k0 + 64);
        }
        #pragma unroll
        for (int mi = 0; mi < MI; ++mi)
            #pragma unroll
            for (int ni = 0; ni < NI; ++ni)
                acc[mi][ni] = __builtin_amdgcn_mfma_f32_16x16x32_bf16(
                    aN[mi], bN[ni], acc[mi][ni], 0, 0, 0);
    }

    int rbase0 = (lane >> 4) * 4;
    #pragma unroll
    for (int ni = 0; ni < NI; ++ni) {
        int col = n_off + ni * 16 + lr;
        float bv = bias[col];
        #pragma unroll
        for (int mi = 0; mi < MI; ++mi) {
            int rbase = m_off + mi * 16 + rbase0;
            #pragma unroll
            for (int r = 0; r < 4; ++r) {
                float v = acc[mi][ni][r] + bv;
                if (RELU) v = fmaxf(v, 0.f);
                size_t idx = (size_t)(rbase + r) * N + col;
                if (MODE == 1) ((unsigned short*)out)[idx] = f2bf(v);
                else           ((float*)out)[idx] = v;
                if (MODE == 2) out2[idx] = f2bf(v);
            }
        }
    }
}

// ---------------------------------------------------------------------------
// Kernel 5: heads GEMM. h7b[4096][512]bf16 @ wcd[64][512]^T + bcd.
// cols 0-29 -> class logits (+fused class softmax), 32-61 -> det logits.
// ---------------------------------------------------------------------------
__global__ __launch_bounds__(256) void heads_gemm_kernel(
    const unsigned short* __restrict__ h7b,
    const unsigned short* __restrict__ wcd, const float* __restrict__ bcd,
    float* __restrict__ class_logits, float* __restrict__ det_logits,
    float* __restrict__ class_prob)
{
    int tid  = threadIdx.x;
    int lane = tid & 63;
    int w    = tid >> 6;
    int lr   = lane & 15;
    int lk   = (lane >> 4) * 8;

    int m_base = blockIdx.x * 256 + w * 64;

    const unsigned short* Ap = h7b + (size_t)(m_base + lr) * 512 + lk;
    const unsigned short* Bp = wcd + (size_t)lr * 512 + lk;

    f32x4 acc[4][4] = {};

    for (int k0 = 0; k0 < 512; k0 += 32) {
        bf16x8 a[4], b[4];
        #pragma unroll
        for (int mi = 0; mi < 4; ++mi)
            a[mi] = *(const bf16x8*)(Ap + (size_t)mi * 16 * 512 + k0);
        #pragma unroll
        for (int ni = 0; ni < 4; ++ni)
            b[ni] = *(const bf16x8*)(Bp + (size_t)ni * 16 * 512 + k0);
        #pragma unroll
        for (int mi = 0; mi < 4; ++mi)
            #pragma unroll
            for (int ni = 0; ni < 4; ++ni)
                acc[mi][ni] = __builtin_amdgcn_mfma_f32_16x16x32_bf16(
                    a[mi], b[ni], acc[mi][ni], 0, 0, 0);
    }

    float b0 = bcd[lr], b1 = bcd[16 + lr], b2 = bcd[32 + lr], b3 = bcd[48 + lr];
    int rgrp = (lane >> 4) * 4;

    #pragma unroll
    for (int mi = 0; mi < 4; ++mi) {
        #pragma unroll
        for (int r = 0; r < 4; ++r) {
            int row = m_base + mi * 16 + rgrp + r;
            float c0 = acc[mi][0][r] + b0;
            float c1 = (lr < 14) ? (acc[mi][1][r] + b1) : -3.4e38f;
            float mx = fmaxf(c0, c1);
            #pragma unroll
            for (int m = 1; m < 16; m <<= 1) mx = fmaxf(mx, __shfl_xor(mx, m));
            float e0 = __expf(c0 - mx);
            float e1 = (lr < 14) ? __expf(c1 - mx) : 0.f;
            float s = e0 + e1;
            #pragma unroll
            for (int m = 1; m < 16; m <<= 1) s += __shfl_xor(s, m);
            float inv = 1.0f / s;

            class_logits[(size_t)row * K_ + lr] = c0;
            class_prob[(size_t)row * K_ + lr]   = e0 * inv;
            det_logits[(size_t)row * K_ + lr]   = acc[mi][2][r] + b2;
            if (lr < 14) {
                class_logits[(size_t)row * K_ + 16 + lr] = c1;
                class_prob[(size_t)row * K_ + 16 + lr]   = e1 * inv;
                det_logits[(size_t)row * K_ + 16 + lr]   = acc[mi][3][r] + b3;
            }
        }
    }
}

// ---------------------------------------------------------------------------
// Kernel 6: det softmax over P (per b,k), joint prob, video prob.
// ---------------------------------------------------------------------------
__global__ __launch_bounds__(256) void det_softmax_kernel(
    const float* __restrict__ det_logits, const float* __restrict__ class_prob,
    float* __restrict__ joint, float* __restrict__ video)
{
    int k = blockIdx.x;
    int b = blockIdx.y;
    int tid = threadIdx.x;
    size_t base = (size_t)b * P_ * K_ + k;

    float v0 = det_logits[base + (size_t)tid * K_];
    float v1 = det_logits[base + (size_t)(tid + 256) * K_];

    __shared__ float red[256];
    red[tid] = fmaxf(v0, v1);
    __syncthreads();
    for (int off = 128; off; off >>= 1) {
        if (tid < off) red[tid] = fmaxf(red[tid], red[tid + off]);
        __syncthreads();
    }
    float mx = red[0];
    __syncthreads();

    float e0 = __expf(v0 - mx), e1 = __expf(v1 - mx);
    red[tid] = e0 + e1;
    __syncthreads();
    for (int off = 128; off; off >>= 1) {
        if (tid < off) red[tid] += red[tid + off];
        __syncthreads();
    }
    float inv = 1.0f / red[0];
    __syncthreads();

    float j0 = class_prob[base + (size_t)tid * K_] * e0 * inv;
    float j1 = class_prob[base + (size_t)(tid + 256) * K_] * e1 * inv;
    joint[base + (size_t)tid * K_] = j0;
    joint[base + (size_t)(tid + 256) * K_] = j1;

    red[tid] = j0 + j1;
    __syncthreads();
    for (int off = 128; off; off >>= 1) {
        if (tid < off) red[tid] += red[tid + off];
        __syncthreads();
    }
    if (tid == 0) video[(size_t)b * K_ + k] = red[0];
}

// ---------------------------------------------------------------------------
extern "C" void kernel_launch(void* const* d_in, const int* in_sizes, int n_in,
                              void* d_out, int out_size, void* d_ws, size_t ws_size,
                              hipStream_t stream)
{
    const float* x     = (const float*)d_in[0];
    const int*   boxes = (const int*)d_in[1];   // staged as int32
    const float* W6 = (const float*)d_in[2];
    const float* b6 = (const float*)d_in[3];
    const float* W7 = (const float*)d_in[4];
    const float* b7 = (const float*)d_in[5];
    const float* Wc = (const float*)d_in[6];
    const float* bc = (const float*)d_in[7];
    const float* Wd = (const float*)d_in[8];
    const float* bd = (const float*)d_in[9];

    float* out          = (float*)d_out;
    float* video        = out;                 // [8,30]
    float* joint        = out + 240;           // [8,512,30]
    float* class_logits = out + 123120;        // [8,512,30]
    float* det_logits   = out + 246000;        // [8,512,30]
    float* h7           = out + 368880;        // [8,512,512] f32

    // workspace (~23 MB of ~512 MB) — all regions 16B-aligned
    unsigned short* wsu   = (unsigned short*)d_ws;
    unsigned short* h6    = wsu;                                  // 4096*1024
    unsigned short* w6b   = h6 + (size_t)4096 * 1024;             // 1024*512
    unsigned short* w7b   = w6b + (size_t)1024 * 512;             // 512*1024
    unsigned short* wcd   = w7b + (size_t)512 * 1024;             // 64*512
    unsigned short* h7b   = wcd + (size_t)64 * 512;               // 4096*512
    unsigned short* feats = h7b + (size_t)4096 * 512;             // 4096*512
    unsigned short* featsT= feats + (size_t)4096 * 512;           // 4096*512
    float* bcd            = (float*)(featsT + (size_t)4096 * 512);// 64
    float* class_prob     = bcd + 64;                             // 122880

    const int M = B_ * P_;   // 4096

    prep_pool_kernel<<<5184, 256, 0, stream>>>(
        x, boxes, featsT, W6, w6b, W7, w7b, Wc, bc, Wd, bd, wcd, bcd);

    transpose_kernel<<<dim3(C_ / 64, P_ / 64, B_), 256, 0, stream>>>(featsT, feats);

    // gemm1: M=4096 K=512 N=1024, block 128x64 (waves 32x64) -> 512 blocks
    gemm_mfma<512, 1, 1, 128, 64, 32, 64>
        <<<dim3(1024 / 64, M / 128), 256, 0, stream>>>(
        feats, w6b, b6, (void*)h6, nullptr, 1024);

    // gemm2: M=4096 K=1024 N=512, block 64x64 (waves 32x32) -> 512 blocks
    gemm_mfma<1024, 1, 2, 64, 64, 32, 32>
        <<<dim3(512 / 64, M / 64), 256, 0, stream>>>(
        h6, w7b, b7, (void*)h7, h7b, 512);

    heads_gemm_kernel<<<16, 256, 0, stream>>>(
        h7b, wcd, bcd, class_logits, det_logits, class_prob);

    det_softmax_kernel<<<dim3(K_, B_), 256, 0, stream>>>(
        det_logits, class_prob, joint, video);
}